// Round 3
// baseline (712.084 us; speedup 1.0000x reference)
//
#include <hip/hip_runtime.h>
#include <stdint.h>

// Shapes: B=32, N=1024, F=512, G=16, S=64, D=256, conv window 32, Cout=512, Tout=993.
// I/O is fp32 (per reference); internal compute bf16 MFMA.
// ROUND 10: k_conv_gemm keeps R9's grid order (batch fastest -> cwT o-tile L2-resident
// per XCD, FETCH 48MB) and the known-safe stage->sync->compute->sync skeleton, but
// B now bypasses LDS: fragments read directly from L2 into registers (b128, natural
// layout). Halves LDS read traffic (was ~1.5x oversubscribed vs MFMA pipe), removes
// B staging issues, LDS/block 32KB->16KB. No sync-structure changes (raw-barrier
// schedules deterministically kill containers; proven R8 + prior session R4-R6).

typedef __bf16  bf16x8 __attribute__((ext_vector_type(8)));
typedef float   f32x4  __attribute__((ext_vector_type(4)));

__device__ __forceinline__ uint16_t f2bf(float f) {
    union { float f; uint32_t u; } x; x.f = f;
    uint32_t r = x.u + 0x7FFFu + ((x.u >> 16) & 1u);   // RTNE
    return (uint16_t)(r >> 16);
}
// async global->LDS, 16B per lane. LDS dest = wave-uniform base + lane*16 (HW rule).
template <typename T>
__device__ __forceinline__ void gl2lds16(const T* g, T* l) {
    __builtin_amdgcn_global_load_lds(
        (const __attribute__((address_space(1))) uint32_t*)g,
        (__attribute__((address_space(3))) uint32_t*)l, 16, 0, 0);
}

// ---------------- fp32 -> bf16 tiled transpose: in (R,C) f32 -> out (C,R) bf16, z = matrix
__global__ void transpose_cvt(const float* __restrict__ in, uint16_t* __restrict__ out,
                              int R, int C) {
    __shared__ float tile[32][33];
    const float* inm = in + (size_t)blockIdx.z * R * C;
    uint16_t* outm = out + (size_t)blockIdx.z * R * C;
    int c0 = blockIdx.x * 32, r0 = blockIdx.y * 32;
    int tx = threadIdx.x, ty = threadIdx.y;            // (32, 8)
    #pragma unroll
    for (int i = 0; i < 32; i += 8)
        tile[ty + i][tx] = inm[(size_t)(r0 + ty + i) * C + (c0 + tx)];
    __syncthreads();
    #pragma unroll
    for (int i = 0; i < 32; i += 8)
        outm[(size_t)(c0 + ty + i) * R + (r0 + tx)] = f2bf(tile[tx][ty + i]);
}

// ---------------- Kernel 1: gathered grouped GEMM -> intermediate (32*1024+64, 256) bf16
// (unchanged from the known-pass round)
__global__ __launch_bounds__(256, 2)
void k_group_gemm(const float*    __restrict__ x,    // (32,1024,512) f32
                  const int*      __restrict__ idx,  // (16,64)
                  const uint16_t* __restrict__ Wt,   // (16,256,512) bf16 (W^T per group)
                  const float*    __restrict__ bias, // (16,256) f32
                  uint16_t*       __restrict__ interm) {
    __shared__ float    smemA[128 * 64];              // 32 KB, 16-slot xor swizzle
    __shared__ uint16_t smemB[128 * 64];              // 16 KB, 8-slot xor swizzle
    __shared__ int sidx[64];
    const int tid  = threadIdx.x;
    const int g    = blockIdx.z;
    const int bp   = blockIdx.y;                      // batches 2bp, 2bp+1
    const int n0   = blockIdx.x * 128;                // d tile base
    const int wave = tid >> 6, lane = tid & 63;
    const int quad = lane >> 4, l15 = lane & 15;
    const int mw = (wave & 1) * 64, nw = (wave >> 1) * 64;

    if (tid < 64) sidx[tid] = idx[g * 64 + tid];
    __syncthreads();

    uint32_t aoffF[8];
    #pragma unroll
    for (int is = 0; is < 8; ++is) {
        int r = wave * 32 + is * 4 + (lane >> 4);     // tile row 0..127
        int b = bp * 2 + (r >> 6), s = r & 63;
        int gc = (lane & 15) ^ (r & 15);              // xor-swizzled 4-float chunk
        aoffF[is] = ((uint32_t)b * 1024u + (uint32_t)sidx[s]) * 512u + (uint32_t)gc * 4u;
    }
    uint32_t boff[4];
    #pragma unroll
    for (int is = 0; is < 4; ++is) {
        int r = wave * 32 + is * 8 + (lane >> 3);
        int gc8 = ((lane & 7) ^ (lane >> 3)) * 8;
        boff[is] = ((uint32_t)(g * 256 + n0 + r)) * 512u + (uint32_t)gc8;
    }

    f32x4 acc[4][4];
    #pragma unroll
    for (int i = 0; i < 4; ++i)
        #pragma unroll
        for (int j = 0; j < 4; ++j)
            #pragma unroll
            for (int c = 0; c < 4; ++c) acc[i][j][c] = 0.f;

    for (int kb = 0; kb < 8; ++kb) {                  // K = 512, BK = 64
        #pragma unroll
        for (int is = 0; is < 8; ++is)
            gl2lds16(x + aoffF[is] + kb * 64, &smemA[(wave * 32 + is * 4) * 64]);
        #pragma unroll
        for (int is = 0; is < 4; ++is)
            gl2lds16(Wt + boff[is] + kb * 64, &smemB[(wave * 32 + is * 8) * 64]);
        __syncthreads();
        #pragma unroll
        for (int ks = 0; ks < 2; ++ks) {
            const int kc = ks * 4 + quad;             // 8-elem k-chunk index 0..7
            bf16x8 af[4], bfr[4];
            #pragma unroll
            for (int i = 0; i < 4; ++i) {
                int m = mw + i * 16 + l15;
                int s0 = (2 * kc) ^ (m & 15);
                int s1 = (2 * kc + 1) ^ (m & 15);
                f32x4 f0 = *(const f32x4*)&smemA[m * 64 + s0 * 4];
                f32x4 f1 = *(const f32x4*)&smemA[m * 64 + s1 * 4];
                #pragma unroll
                for (int j = 0; j < 4; ++j) { af[i][j] = (__bf16)f0[j]; af[i][j + 4] = (__bf16)f1[j]; }
            }
            #pragma unroll
            for (int j = 0; j < 4; ++j) {
                int n = nw + j * 16 + l15;
                bfr[j] = *(const bf16x8*)&smemB[(n * 8 + (kc ^ (n & 7))) * 8];
            }
            #pragma unroll
            for (int i = 0; i < 4; ++i)
                #pragma unroll
                for (int j = 0; j < 4; ++j)
                    acc[i][j] = __builtin_amdgcn_mfma_f32_16x16x32_bf16(af[i], bfr[j], acc[i][j], 0, 0, 0);
        }
        __syncthreads();
    }

    #pragma unroll
    for (int j = 0; j < 4; ++j) {
        int col = n0 + nw + j * 16 + l15;
        float bv = bias[g * 256 + col];
        #pragma unroll
        for (int i = 0; i < 4; ++i) {
            int mbase = mw + i * 16 + quad * 4;
            #pragma unroll
            for (int r = 0; r < 4; ++r) {
                int m = mbase + r;
                int b = bp * 2 + (m >> 6), s = m & 63;
                interm[((size_t)b * 1024 + g * 64 + s) * 256 + col] = f2bf(acc[i][j][r] + bv);
            }
        }
    }
}

// ---------------- Kernel 2: conv as GEMM. M=993(per batch, tiled 128), N=512, K=8192
// grid: (x=32 batches, y=8 t-tiles, z=4 o-tiles) -- batch fastest: each XCD keeps its
// 2MB cwT o-tile L2-resident. A (interm) staged in LDS via global_load_lds as before;
// B (cwT) fragments read DIRECTLY from L2 into registers -- no LDS staging, no LDS
// reads for B. Per wave per K-step LDS reads halve (16KB->8KB) putting the MFMA pipe
// back on the critical path. Sync skeleton unchanged: stage -> sync -> compute -> sync.
__global__ __launch_bounds__(256, 2)
void k_conv_gemm(const uint16_t* __restrict__ interm, // (32*1024+64, 256) bf16
                 const uint16_t* __restrict__ cwT,    // (512, 8192) bf16: [o][k*256+c]
                 const float*    __restrict__ cb,     // (512) f32
                 float*          __restrict__ y) {    // (32, 993, 512) f32
    __shared__ uint16_t smem[8192];                   // A only: 128 rows x 64, 16 KB
    const int tid  = threadIdx.x;
    const int n0   = blockIdx.z * 128;                // out-channel tile (slowest)
    const int t0   = blockIdx.y * 128;                // time tile
    const int nb   = blockIdx.x;                      // batch (fastest)
    const int wave = tid >> 6, lane = tid & 63;
    const int quad = lane >> 4, l15 = lane & 15;
    const int mw = (wave & 1) * 64, nw = (wave >> 1) * 64;

    const int srow = wave * 32 + (lane >> 3);
    const int gc8  = ((lane & 7) ^ (lane >> 3)) * 8;

    // A staging offsets (swizzled source so linear LDS dest + swizzled read match)
    uint32_t aoff[4];
    #pragma unroll
    for (int is = 0; is < 4; ++is) {
        int r = srow + is * 8;
        aoff[is] = ((uint32_t)(nb * 1024 + t0 + r)) * 256u + gc8;
    }
    // B direct-read base pointers: row (n0+nw+j*16+l15), this quad's 16B sub-chunk.
    // Per K-step kb: columns kb*64 + (ks*4+quad)*8 -> base + kb*64 + ks*32.
    const uint16_t* bbase[4];
    #pragma unroll
    for (int j = 0; j < 4; ++j)
        bbase[j] = cwT + (size_t)(n0 + nw + j * 16 + l15) * 8192 + quad * 8;

    f32x4 acc[4][4];
    #pragma unroll
    for (int i = 0; i < 4; ++i)
        #pragma unroll
        for (int j = 0; j < 4; ++j)
            #pragma unroll
            for (int c = 0; c < 4; ++c) acc[i][j][c] = 0.f;

    for (int kb = 0; kb < 128; ++kb) {                // K = 8192, BK = 64
        const int k  = kb >> 2;                       // conv tap 0..31
        const int c0 = (kb & 3) * 64;                 // channel block
        #pragma unroll
        for (int is = 0; is < 4; ++is)
            gl2lds16(interm + aoff[is] + (uint32_t)k * 256u + c0,
                     &smem[(wave * 32 + is * 8) * 64]);
        // B fragments: issue before the barrier (independent of LDS) so the L2
        // latency hides under the staging drain.
        bf16x8 bfr[2][4];
        #pragma unroll
        for (int ks = 0; ks < 2; ++ks)
            #pragma unroll
            for (int j = 0; j < 4; ++j)
                bfr[ks][j] = *(const bf16x8*)(bbase[j] + ks * 32);
        __syncthreads();
        #pragma unroll
        for (int ks = 0; ks < 2; ++ks) {
            const int kc = ks * 4 + quad;
            bf16x8 af[4];
            #pragma unroll
            for (int i = 0; i < 4; ++i) {
                int m = mw + i * 16 + l15;
                af[i] = *(const bf16x8*)&smem[(m * 8 + (kc ^ (m & 7))) * 8];
            }
            #pragma unroll
            for (int i = 0; i < 4; ++i)
                #pragma unroll
                for (int j = 0; j < 4; ++j)
                    acc[i][j] = __builtin_amdgcn_mfma_f32_16x16x32_bf16(af[i], bfr[ks][j], acc[i][j], 0, 0, 0);
        }
        __syncthreads();
        #pragma unroll
        for (int j = 0; j < 4; ++j) bbase[j] += 64;
    }

    // epilogue: +conv_b(f32), leaky relu, store f32, valid t < 993
    #pragma unroll
    for (int j = 0; j < 4; ++j) {
        int col = n0 + nw + j * 16 + l15;
        float bv = cb[col];
        #pragma unroll
        for (int i = 0; i < 4; ++i) {
            int tb = t0 + mw + i * 16 + quad * 4;
            #pragma unroll
            for (int r = 0; r < 4; ++r) {
                int t = tb + r;
                if (t < 993) {
                    float v = acc[i][j][r] + bv;
                    v = (v >= 0.f) ? v : 0.2f * v;
                    y[((size_t)nb * 993 + t) * 512 + col] = v;
                }
            }
        }
    }
}

extern "C" void kernel_launch(void* const* d_in, const int* in_sizes, int n_in,
                              void* d_out, int out_size, void* d_ws, size_t ws_size,
                              hipStream_t stream) {
    const float* x   = (const float*)d_in[0];   // (32,1024,512) f32
    const int*   idx = (const int*)  d_in[1];   // (16,64) i32
    const float* W   = (const float*)d_in[2];   // (16,512,256) f32
    const float* b   = (const float*)d_in[3];   // (16,256) f32
    const float* cw  = (const float*)d_in[4];   // (32,256,512) f32
    const float* cb  = (const float*)d_in[5];   // (512) f32
    float* out = (float*)d_out;                 // (32,993,512) f32

    // workspace (bf16 elems): interm (32832,256) | Wt (16,256,512) | cwT (512,8192)  ~29.4 MB
    uint16_t* interm = (uint16_t*)d_ws;
    uint16_t* Wt  = interm + (size_t)32832 * 256;
    uint16_t* cwT = Wt + (size_t)16 * 256 * 512;

    // W (g,512,256) f32 -> Wt (g,256,512) bf16
    transpose_cvt<<<dim3(256 / 32, 512 / 32, 16), dim3(32, 8), 0, stream>>>(W, Wt, 512, 256);
    // conv_w (8192,512) f32 -> cwT (512,8192) bf16
    transpose_cvt<<<dim3(512 / 32, 8192 / 32, 1), dim3(32, 8), 0, stream>>>(cw, cwT, 8192, 512);

    k_group_gemm<<<dim3(2, 16, 16), 256, 0, stream>>>(x, idx, Wt, b, interm);
    k_conv_gemm <<<dim3(32, 8, 4),  256, 0, stream>>>(interm, cwT, cb, out);
}

// Round 4
// 408.646 us; speedup vs baseline: 1.7425x; 1.7425x over previous
//
#include <hip/hip_runtime.h>
#include <stdint.h>

// Shapes: B=32, N=1024, F=512, G=16, S=64, D=256, conv window 32, Cout=512, Tout=993.
// I/O is fp32 (per reference); internal compute bf16 MFMA.
// ROUND 11: revert R10's B-direct-from-L2 (uncoalesced 64-line fan-out per load ->
// latency-bound, 599us). Back to R9's kernel (255us conv, FETCH 48MB), plus the one
// safe schedule change: DOUBLE-BUFFERED LDS with ONE __syncthreads per K-step.
// stage(t+1)->buf^1 issued before compute(t); the compiler's barrier drain
// (vmcnt(0)+lgkmcnt(0)) lands the loads and protects the buffer. No raw s_barrier,
// no manual vmcnt (those deterministically kill containers: R8 + prior R4-R6).

typedef __bf16  bf16x8 __attribute__((ext_vector_type(8)));
typedef float   f32x4  __attribute__((ext_vector_type(4)));

__device__ __forceinline__ uint16_t f2bf(float f) {
    union { float f; uint32_t u; } x; x.f = f;
    uint32_t r = x.u + 0x7FFFu + ((x.u >> 16) & 1u);   // RTNE
    return (uint16_t)(r >> 16);
}
// async global->LDS, 16B per lane. LDS dest = wave-uniform base + lane*16 (HW rule).
template <typename T>
__device__ __forceinline__ void gl2lds16(const T* g, T* l) {
    __builtin_amdgcn_global_load_lds(
        (const __attribute__((address_space(1))) uint32_t*)g,
        (__attribute__((address_space(3))) uint32_t*)l, 16, 0, 0);
}

// ---------------- fp32 -> bf16 tiled transpose: in (R,C) f32 -> out (C,R) bf16, z = matrix
__global__ void transpose_cvt(const float* __restrict__ in, uint16_t* __restrict__ out,
                              int R, int C) {
    __shared__ float tile[32][33];
    const float* inm = in + (size_t)blockIdx.z * R * C;
    uint16_t* outm = out + (size_t)blockIdx.z * R * C;
    int c0 = blockIdx.x * 32, r0 = blockIdx.y * 32;
    int tx = threadIdx.x, ty = threadIdx.y;            // (32, 8)
    #pragma unroll
    for (int i = 0; i < 32; i += 8)
        tile[ty + i][tx] = inm[(size_t)(r0 + ty + i) * C + (c0 + tx)];
    __syncthreads();
    #pragma unroll
    for (int i = 0; i < 32; i += 8)
        outm[(size_t)(c0 + ty + i) * R + (r0 + tx)] = f2bf(tile[tx][ty + i]);
}

// ---------------- Kernel 1: gathered grouped GEMM -> intermediate (32*1024+64, 256) bf16
// (unchanged from the known-pass round)
__global__ __launch_bounds__(256, 2)
void k_group_gemm(const float*    __restrict__ x,    // (32,1024,512) f32
                  const int*      __restrict__ idx,  // (16,64)
                  const uint16_t* __restrict__ Wt,   // (16,256,512) bf16 (W^T per group)
                  const float*    __restrict__ bias, // (16,256) f32
                  uint16_t*       __restrict__ interm) {
    __shared__ float    smemA[128 * 64];              // 32 KB, 16-slot xor swizzle
    __shared__ uint16_t smemB[128 * 64];              // 16 KB, 8-slot xor swizzle
    __shared__ int sidx[64];
    const int tid  = threadIdx.x;
    const int g    = blockIdx.z;
    const int bp   = blockIdx.y;                      // batches 2bp, 2bp+1
    const int n0   = blockIdx.x * 128;                // d tile base
    const int wave = tid >> 6, lane = tid & 63;
    const int quad = lane >> 4, l15 = lane & 15;
    const int mw = (wave & 1) * 64, nw = (wave >> 1) * 64;

    if (tid < 64) sidx[tid] = idx[g * 64 + tid];
    __syncthreads();

    uint32_t aoffF[8];
    #pragma unroll
    for (int is = 0; is < 8; ++is) {
        int r = wave * 32 + is * 4 + (lane >> 4);     // tile row 0..127
        int b = bp * 2 + (r >> 6), s = r & 63;
        int gc = (lane & 15) ^ (r & 15);              // xor-swizzled 4-float chunk
        aoffF[is] = ((uint32_t)b * 1024u + (uint32_t)sidx[s]) * 512u + (uint32_t)gc * 4u;
    }
    uint32_t boff[4];
    #pragma unroll
    for (int is = 0; is < 4; ++is) {
        int r = wave * 32 + is * 8 + (lane >> 3);
        int gc8 = ((lane & 7) ^ (lane >> 3)) * 8;
        boff[is] = ((uint32_t)(g * 256 + n0 + r)) * 512u + (uint32_t)gc8;
    }

    f32x4 acc[4][4];
    #pragma unroll
    for (int i = 0; i < 4; ++i)
        #pragma unroll
        for (int j = 0; j < 4; ++j)
            #pragma unroll
            for (int c = 0; c < 4; ++c) acc[i][j][c] = 0.f;

    for (int kb = 0; kb < 8; ++kb) {                  // K = 512, BK = 64
        #pragma unroll
        for (int is = 0; is < 8; ++is)
            gl2lds16(x + aoffF[is] + kb * 64, &smemA[(wave * 32 + is * 4) * 64]);
        #pragma unroll
        for (int is = 0; is < 4; ++is)
            gl2lds16(Wt + boff[is] + kb * 64, &smemB[(wave * 32 + is * 8) * 64]);
        __syncthreads();
        #pragma unroll
        for (int ks = 0; ks < 2; ++ks) {
            const int kc = ks * 4 + quad;             // 8-elem k-chunk index 0..7
            bf16x8 af[4], bfr[4];
            #pragma unroll
            for (int i = 0; i < 4; ++i) {
                int m = mw + i * 16 + l15;
                int s0 = (2 * kc) ^ (m & 15);
                int s1 = (2 * kc + 1) ^ (m & 15);
                f32x4 f0 = *(const f32x4*)&smemA[m * 64 + s0 * 4];
                f32x4 f1 = *(const f32x4*)&smemA[m * 64 + s1 * 4];
                #pragma unroll
                for (int j = 0; j < 4; ++j) { af[i][j] = (__bf16)f0[j]; af[i][j + 4] = (__bf16)f1[j]; }
            }
            #pragma unroll
            for (int j = 0; j < 4; ++j) {
                int n = nw + j * 16 + l15;
                bfr[j] = *(const bf16x8*)&smemB[(n * 8 + (kc ^ (n & 7))) * 8];
            }
            #pragma unroll
            for (int i = 0; i < 4; ++i)
                #pragma unroll
                for (int j = 0; j < 4; ++j)
                    acc[i][j] = __builtin_amdgcn_mfma_f32_16x16x32_bf16(af[i], bfr[j], acc[i][j], 0, 0, 0);
        }
        __syncthreads();
    }

    #pragma unroll
    for (int j = 0; j < 4; ++j) {
        int col = n0 + nw + j * 16 + l15;
        float bv = bias[g * 256 + col];
        #pragma unroll
        for (int i = 0; i < 4; ++i) {
            int mbase = mw + i * 16 + quad * 4;
            #pragma unroll
            for (int r = 0; r < 4; ++r) {
                int m = mbase + r;
                int b = bp * 2 + (m >> 6), s = m & 63;
                interm[((size_t)b * 1024 + g * 64 + s) * 256 + col] = f2bf(acc[i][j][r] + bv);
            }
        }
    }
}

// ---------------- Kernel 2: conv as GEMM. M=993(per batch, tiled 128), N=512, K=8192
// grid: (x=32 batches, y=8 t-tiles, z=4 o-tiles) -- batch fastest: each XCD keeps its
// 2MB cwT o-tile L2-resident (R9 win, FETCH 48MB). A and B staged via global_load_lds
// into DOUBLE-BUFFERED LDS; stage(t+1) issued before compute(t); ONE __syncthreads
// per K-step both drains the async loads and protects the buffer being overwritten
// next iteration. Known-safe sync primitive only.
__global__ __launch_bounds__(256, 2)
void k_conv_gemm(const uint16_t* __restrict__ interm, // (32*1024+64, 256) bf16
                 const uint16_t* __restrict__ cwT,    // (512, 8192) bf16: [o][k*256+c]
                 const float*    __restrict__ cb,     // (512) f32
                 float*          __restrict__ y) {    // (32, 993, 512) f32
    __shared__ uint16_t smem[2][16384];               // 64 KB: [buf][A:0..8192 | B:8192..16384]
    const int tid  = threadIdx.x;
    const int n0   = blockIdx.z * 128;                // out-channel tile (slowest)
    const int t0   = blockIdx.y * 128;                // time tile
    const int nb   = blockIdx.x;                      // batch (fastest)
    const int wave = tid >> 6, lane = tid & 63;
    const int quad = lane >> 4, l15 = lane & 15;
    const int mw = (wave & 1) * 64, nw = (wave >> 1) * 64;

    const int srow = wave * 32 + (lane >> 3);
    const int gc8  = ((lane & 7) ^ (lane >> 3)) * 8;

    uint32_t aoff[4], boff[4];
    #pragma unroll
    for (int is = 0; is < 4; ++is) {
        int r = srow + is * 8;
        aoff[is] = ((uint32_t)(nb * 1024 + t0 + r)) * 256u + gc8;
        boff[is] = ((uint32_t)(n0 + r)) * 8192u + gc8;
    }

    // stage K-step kb into buffer buf (A: interm tap k chan-block c0; B: cwT cols)
    auto stage = [&](int kb, uint16_t* buf) {
        const int k  = kb >> 2;                       // conv tap 0..31
        const int c0 = (kb & 3) * 64;                 // channel block
        #pragma unroll
        for (int is = 0; is < 4; ++is) {
            gl2lds16(interm + aoff[is] + (uint32_t)k * 256u + c0,
                     &buf[(wave * 32 + is * 8) * 64]);
            gl2lds16(cwT + boff[is] + (uint32_t)kb * 64u,
                     &buf[8192 + (wave * 32 + is * 8) * 64]);
        }
    };

    f32x4 acc[4][4];
    #pragma unroll
    for (int i = 0; i < 4; ++i)
        #pragma unroll
        for (int j = 0; j < 4; ++j)
            #pragma unroll
            for (int c = 0; c < 4; ++c) acc[i][j][c] = 0.f;

    stage(0, smem[0]);
    __syncthreads();                                  // tile 0 landed

    for (int kb = 0; kb < 128; ++kb) {                // K = 8192, BK = 64
        uint16_t* cur = smem[kb & 1];
        uint16_t* nxt = smem[(kb & 1) ^ 1];
        if (kb < 127) stage(kb + 1, nxt);             // async; overlaps compute below
        #pragma unroll
        for (int ks = 0; ks < 2; ++ks) {
            const int kc = ks * 4 + quad;
            bf16x8 af[4], bfr[4];
            #pragma unroll
            for (int i = 0; i < 4; ++i) {
                int m = mw + i * 16 + l15;
                af[i] = *(const bf16x8*)&cur[(m * 8 + (kc ^ (m & 7))) * 8];
            }
            #pragma unroll
            for (int j = 0; j < 4; ++j) {
                int n = nw + j * 16 + l15;
                bfr[j] = *(const bf16x8*)&cur[8192 + (n * 8 + (kc ^ (n & 7))) * 8];
            }
            #pragma unroll
            for (int i = 0; i < 4; ++i)
                #pragma unroll
                for (int j = 0; j < 4; ++j)
                    acc[i][j] = __builtin_amdgcn_mfma_f32_16x16x32_bf16(af[i], bfr[j], acc[i][j], 0, 0, 0);
        }
        // single barrier: drains stage(kb+1) (vmcnt) and guards cur from being
        // overwritten by iteration kb+1's stage(kb+2).
        __syncthreads();
    }

    // epilogue: +conv_b(f32), leaky relu, store f32, valid t < 993
    #pragma unroll
    for (int j = 0; j < 4; ++j) {
        int col = n0 + nw + j * 16 + l15;
        float bv = cb[col];
        #pragma unroll
        for (int i = 0; i < 4; ++i) {
            int tb = t0 + mw + i * 16 + quad * 4;
            #pragma unroll
            for (int r = 0; r < 4; ++r) {
                int t = tb + r;
                if (t < 993) {
                    float v = acc[i][j][r] + bv;
                    v = (v >= 0.f) ? v : 0.2f * v;
                    y[((size_t)nb * 993 + t) * 512 + col] = v;
                }
            }
        }
    }
}

extern "C" void kernel_launch(void* const* d_in, const int* in_sizes, int n_in,
                              void* d_out, int out_size, void* d_ws, size_t ws_size,
                              hipStream_t stream) {
    const float* x   = (const float*)d_in[0];   // (32,1024,512) f32
    const int*   idx = (const int*)  d_in[1];   // (16,64) i32
    const float* W   = (const float*)d_in[2];   // (16,512,256) f32
    const float* b   = (const float*)d_in[3];   // (16,256) f32
    const float* cw  = (const float*)d_in[4];   // (32,256,512) f32
    const float* cb  = (const float*)d_in[5];   // (512) f32
    float* out = (float*)d_out;                 // (32,993,512) f32

    // workspace (bf16 elems): interm (32832,256) | Wt (16,256,512) | cwT (512,8192)  ~29.4 MB
    uint16_t* interm = (uint16_t*)d_ws;
    uint16_t* Wt  = interm + (size_t)32832 * 256;
    uint16_t* cwT = Wt + (size_t)16 * 256 * 512;

    // W (g,512,256) f32 -> Wt (g,256,512) bf16
    transpose_cvt<<<dim3(256 / 32, 512 / 32, 16), dim3(32, 8), 0, stream>>>(W, Wt, 512, 256);
    // conv_w (8192,512) f32 -> cwT (512,8192) bf16
    transpose_cvt<<<dim3(512 / 32, 8192 / 32, 1), dim3(32, 8), 0, stream>>>(cw, cwT, 8192, 512);

    k_group_gemm<<<dim3(2, 16, 16), 256, 0, stream>>>(x, idx, Wt, b, interm);
    k_conv_gemm <<<dim3(32, 8, 4),  256, 0, stream>>>(interm, cwT, cb, out);
}

// Round 6
// 381.132 us; speedup vs baseline: 1.8683x; 1.0722x over previous
//
#include <hip/hip_runtime.h>
#include <stdint.h>

// Shapes: B=32, N=1024, F=512, G=16, S=64, D=256, conv window 32, Cout=512, Tout=993.
// I/O is fp32 (per reference); internal compute bf16 MFMA.
// ROUND 13: k_group reverted to the PROVEN R9 path (it is memory-bound ~35us; the R12
// bf16-gather rework was wrong-theory and died at container level anyway). Conv gets a
// GEOMETRY-ONLY change (the edit class that has always passed): per-wave tile 64x64 ->
// 64x128. Per wave per K-step: 24 ds_read_b128 (288cyc) for 64 MFMA (310cyc) -> matrix
// pipe finally exceeds LDS pipe (was 16 reads/192cyc vs 32 MFMA/155cyc = LDS-starved,
// the 54% MfmaUtil plateau). Block 128x256 (4 waves 2x2), grid (32,8,2)=512=2/CU,
// LDS 48KB, barrier count per FLOP halves. Same staging, same swizzle, same 2-barrier
// skeleton. No sync changes, no new kernels, no ws branch.

typedef __bf16  bf16x8 __attribute__((ext_vector_type(8)));
typedef float   f32x4  __attribute__((ext_vector_type(4)));

__device__ __forceinline__ uint16_t f2bf(float f) {
    union { float f; uint32_t u; } x; x.f = f;
    uint32_t r = x.u + 0x7FFFu + ((x.u >> 16) & 1u);   // RTNE
    return (uint16_t)(r >> 16);
}
// async global->LDS, 16B per lane. LDS dest = wave-uniform base + lane*16 (HW rule).
template <typename T>
__device__ __forceinline__ void gl2lds16(const T* g, T* l) {
    __builtin_amdgcn_global_load_lds(
        (const __attribute__((address_space(1))) uint32_t*)g,
        (__attribute__((address_space(3))) uint32_t*)l, 16, 0, 0);
}

// ---------------- fp32 -> bf16 tiled transpose: in (R,C) f32 -> out (C,R) bf16, z = matrix
__global__ void transpose_cvt(const float* __restrict__ in, uint16_t* __restrict__ out,
                              int R, int C) {
    __shared__ float tile[32][33];
    const float* inm = in + (size_t)blockIdx.z * R * C;
    uint16_t* outm = out + (size_t)blockIdx.z * R * C;
    int c0 = blockIdx.x * 32, r0 = blockIdx.y * 32;
    int tx = threadIdx.x, ty = threadIdx.y;            // (32, 8)
    #pragma unroll
    for (int i = 0; i < 32; i += 8)
        tile[ty + i][tx] = inm[(size_t)(r0 + ty + i) * C + (c0 + tx)];
    __syncthreads();
    #pragma unroll
    for (int i = 0; i < 32; i += 8)
        outm[(size_t)(c0 + ty + i) * R + (r0 + tx)] = f2bf(tile[tx][ty + i]);
}

// ---------------- Kernel 1: gathered grouped GEMM -> intermediate (32*1024+64, 256) bf16
// (byte-identical to the proven R9 kernel)
__global__ __launch_bounds__(256, 2)
void k_group_gemm(const float*    __restrict__ x,    // (32,1024,512) f32
                  const int*      __restrict__ idx,  // (16,64)
                  const uint16_t* __restrict__ Wt,   // (16,256,512) bf16 (W^T per group)
                  const float*    __restrict__ bias, // (16,256) f32
                  uint16_t*       __restrict__ interm) {
    __shared__ float    smemA[128 * 64];              // 32 KB, 16-slot xor swizzle
    __shared__ uint16_t smemB[128 * 64];              // 16 KB, 8-slot xor swizzle
    __shared__ int sidx[64];
    const int tid  = threadIdx.x;
    const int g    = blockIdx.z;
    const int bp   = blockIdx.y;                      // batches 2bp, 2bp+1
    const int n0   = blockIdx.x * 128;                // d tile base
    const int wave = tid >> 6, lane = tid & 63;
    const int quad = lane >> 4, l15 = lane & 15;
    const int mw = (wave & 1) * 64, nw = (wave >> 1) * 64;

    if (tid < 64) sidx[tid] = idx[g * 64 + tid];
    __syncthreads();

    uint32_t aoffF[8];
    #pragma unroll
    for (int is = 0; is < 8; ++is) {
        int r = wave * 32 + is * 4 + (lane >> 4);     // tile row 0..127
        int b = bp * 2 + (r >> 6), s = r & 63;
        int gc = (lane & 15) ^ (r & 15);              // xor-swizzled 4-float chunk
        aoffF[is] = ((uint32_t)b * 1024u + (uint32_t)sidx[s]) * 512u + (uint32_t)gc * 4u;
    }
    uint32_t boff[4];
    #pragma unroll
    for (int is = 0; is < 4; ++is) {
        int r = wave * 32 + is * 8 + (lane >> 3);
        int gc8 = ((lane & 7) ^ (lane >> 3)) * 8;
        boff[is] = ((uint32_t)(g * 256 + n0 + r)) * 512u + (uint32_t)gc8;
    }

    f32x4 acc[4][4];
    #pragma unroll
    for (int i = 0; i < 4; ++i)
        #pragma unroll
        for (int j = 0; j < 4; ++j)
            #pragma unroll
            for (int c = 0; c < 4; ++c) acc[i][j][c] = 0.f;

    for (int kb = 0; kb < 8; ++kb) {                  // K = 512, BK = 64
        #pragma unroll
        for (int is = 0; is < 8; ++is)
            gl2lds16(x + aoffF[is] + kb * 64, &smemA[(wave * 32 + is * 4) * 64]);
        #pragma unroll
        for (int is = 0; is < 4; ++is)
            gl2lds16(Wt + boff[is] + kb * 64, &smemB[(wave * 32 + is * 8) * 64]);
        __syncthreads();
        #pragma unroll
        for (int ks = 0; ks < 2; ++ks) {
            const int kc = ks * 4 + quad;             // 8-elem k-chunk index 0..7
            bf16x8 af[4], bfr[4];
            #pragma unroll
            for (int i = 0; i < 4; ++i) {
                int m = mw + i * 16 + l15;
                int s0 = (2 * kc) ^ (m & 15);
                int s1 = (2 * kc + 1) ^ (m & 15);
                f32x4 f0 = *(const f32x4*)&smemA[m * 64 + s0 * 4];
                f32x4 f1 = *(const f32x4*)&smemA[m * 64 + s1 * 4];
                #pragma unroll
                for (int j = 0; j < 4; ++j) { af[i][j] = (__bf16)f0[j]; af[i][j + 4] = (__bf16)f1[j]; }
            }
            #pragma unroll
            for (int j = 0; j < 4; ++j) {
                int n = nw + j * 16 + l15;
                bfr[j] = *(const bf16x8*)&smemB[(n * 8 + (kc ^ (n & 7))) * 8];
            }
            #pragma unroll
            for (int i = 0; i < 4; ++i)
                #pragma unroll
                for (int j = 0; j < 4; ++j)
                    acc[i][j] = __builtin_amdgcn_mfma_f32_16x16x32_bf16(af[i], bfr[j], acc[i][j], 0, 0, 0);
        }
        __syncthreads();
    }

    #pragma unroll
    for (int j = 0; j < 4; ++j) {
        int col = n0 + nw + j * 16 + l15;
        float bv = bias[g * 256 + col];
        #pragma unroll
        for (int i = 0; i < 4; ++i) {
            int mbase = mw + i * 16 + quad * 4;
            #pragma unroll
            for (int r = 0; r < 4; ++r) {
                int m = mbase + r;
                int b = bp * 2 + (m >> 6), s = m & 63;
                interm[((size_t)b * 1024 + g * 64 + s) * 256 + col] = f2bf(acc[i][j][r] + bv);
            }
        }
    }
}

// ---------------- Kernel 2: conv as GEMM. Block 128(t) x 256(o), per-wave 64x128.
// grid: (x=32 batches fastest, y=8 t-tiles, z=2 o-tiles) = 512 blocks = 2/CU.
// Per wave per K-step: 24 ds_read_b128 (288cyc) feeding 64 MFMA (310cyc) -> MFMA-bound.
// LDS: A[128][64] 16KB + B[256][64] 32KB = 48KB. Same XOR-chunk involution, same
// stage->sync->compute->sync skeleton as every passing round.
__global__ __launch_bounds__(256, 2)
void k_conv_gemm(const uint16_t* __restrict__ interm, // (32*1024+64, 256) bf16
                 const uint16_t* __restrict__ cwT,    // (512, 8192) bf16: [o][k*256+c]
                 const float*    __restrict__ cb,     // (512) f32
                 float*          __restrict__ y) {    // (32, 993, 512) f32
    __shared__ uint16_t smem[8192 + 16384];           // A:[0,8192) B:[8192,24576) 48KB
    const int tid  = threadIdx.x;
    const int n0   = blockIdx.z * 256;                // out-channel tile (slowest)
    const int t0   = blockIdx.y * 128;                // time tile
    const int nb   = blockIdx.x;                      // batch (fastest)
    const int wave = tid >> 6, lane = tid & 63;
    const int quad = lane >> 4, l15 = lane & 15;
    const int mw = (wave & 1) * 64;                   // wave row base (2 row-waves)
    const int nw = (wave >> 1) * 128;                 // wave col base (2 col-waves)

    const int l8r = lane >> 3;
    const int gc8 = ((lane & 7) ^ l8r) * 8;           // xor-swizzled 8-elem chunk

    uint32_t aoff[4], boff[8];
    #pragma unroll
    for (int is = 0; is < 4; ++is) {
        int r = wave * 32 + is * 8 + l8r;             // A tile row 0..127
        aoff[is] = ((uint32_t)(nb * 1024 + t0 + r)) * 256u + gc8;
    }
    #pragma unroll
    for (int is = 0; is < 8; ++is) {
        int r = wave * 64 + is * 8 + l8r;             // B tile row 0..255
        boff[is] = ((uint32_t)(n0 + r)) * 8192u + gc8;
    }

    f32x4 acc[4][8];
    #pragma unroll
    for (int i = 0; i < 4; ++i)
        #pragma unroll
        for (int j = 0; j < 8; ++j)
            #pragma unroll
            for (int c = 0; c < 4; ++c) acc[i][j][c] = 0.f;

    for (int kb = 0; kb < 128; ++kb) {                // K = 8192, BK = 64
        const int k  = kb >> 2;                       // conv tap 0..31
        const int c0 = (kb & 3) * 64;                 // channel block
        #pragma unroll
        for (int is = 0; is < 4; ++is)
            gl2lds16(interm + aoff[is] + (uint32_t)k * 256u + c0,
                     &smem[(wave * 32 + is * 8) * 64]);
        #pragma unroll
        for (int is = 0; is < 8; ++is)
            gl2lds16(cwT + boff[is] + (uint32_t)kb * 64u,
                     &smem[8192 + (wave * 64 + is * 8) * 64]);
        __syncthreads();
        #pragma unroll
        for (int ks = 0; ks < 2; ++ks) {
            const int kc = ks * 4 + quad;
            bf16x8 af[4], bfr[8];
            #pragma unroll
            for (int i = 0; i < 4; ++i) {
                int m = mw + i * 16 + l15;
                af[i] = *(const bf16x8*)&smem[(m * 8 + (kc ^ (m & 7))) * 8];
            }
            #pragma unroll
            for (int j = 0; j < 8; ++j) {
                int n = nw + j * 16 + l15;
                bfr[j] = *(const bf16x8*)&smem[8192 + (n * 8 + (kc ^ (n & 7))) * 8];
            }
            #pragma unroll
            for (int i = 0; i < 4; ++i)
                #pragma unroll
                for (int j = 0; j < 8; ++j)
                    acc[i][j] = __builtin_amdgcn_mfma_f32_16x16x32_bf16(af[i], bfr[j], acc[i][j], 0, 0, 0);
        }
        __syncthreads();
    }

    // epilogue: +conv_b(f32), leaky relu, store f32, valid t < 993
    #pragma unroll
    for (int j = 0; j < 8; ++j) {
        int col = n0 + nw + j * 16 + l15;
        float bv = cb[col];
        #pragma unroll
        for (int i = 0; i < 4; ++i) {
            int tb = t0 + mw + i * 16 + quad * 4;
            #pragma unroll
            for (int r = 0; r < 4; ++r) {
                int t = tb + r;
                if (t < 993) {
                    float v = acc[i][j][r] + bv;
                    v = (v >= 0.f) ? v : 0.2f * v;
                    y[((size_t)nb * 993 + t) * 512 + col] = v;
                }
            }
        }
    }
}

extern "C" void kernel_launch(void* const* d_in, const int* in_sizes, int n_in,
                              void* d_out, int out_size, void* d_ws, size_t ws_size,
                              hipStream_t stream) {
    const float* x   = (const float*)d_in[0];   // (32,1024,512) f32
    const int*   idx = (const int*)  d_in[1];   // (16,64) i32
    const float* W   = (const float*)d_in[2];   // (16,512,256) f32
    const float* b   = (const float*)d_in[3];   // (16,256) f32
    const float* cw  = (const float*)d_in[4];   // (32,256,512) f32
    const float* cb  = (const float*)d_in[5];   // (512) f32
    float* out = (float*)d_out;                 // (32,993,512) f32

    // workspace (bf16 elems): interm (32832,256) | Wt (16,256,512) | cwT (512,8192)  ~29.4 MB
    uint16_t* interm = (uint16_t*)d_ws;
    uint16_t* Wt  = interm + (size_t)32832 * 256;
    uint16_t* cwT = Wt + (size_t)16 * 256 * 512;

    // W (g,512,256) f32 -> Wt (g,256,512) bf16
    transpose_cvt<<<dim3(256 / 32, 512 / 32, 16), dim3(32, 8), 0, stream>>>(W, Wt, 512, 256);
    // conv_w (8192,512) f32 -> cwT (512,8192) bf16
    transpose_cvt<<<dim3(512 / 32, 8192 / 32, 1), dim3(32, 8), 0, stream>>>(cw, cwT, 8192, 512);

    k_group_gemm<<<dim3(2, 16, 16), 256, 0, stream>>>(x, idx, Wt, b, interm);
    k_conv_gemm <<<dim3(32, 8, 2),  256, 0, stream>>>(interm, cwT, cb, out);
}

// Round 7
// 365.626 us; speedup vs baseline: 1.9476x; 1.0424x over previous
//
#include <hip/hip_runtime.h>
#include <stdint.h>

// Shapes: B=32, N=1024, F=512, G=16, S=64, D=256, conv window 32, Cout=512, Tout=993.
// I/O is fp32 (per reference); internal compute bf16 MFMA.
// ROUND 14: conv = R13 exact copy (248us plateau: 64x128 wave tile, batch-fastest grid,
// FETCH 41MB). k_group reworked IN PLACE (same kernel count/ws/skeleton): A reg-staged
// as bf16 (global f32x4 -> regs -> cast -> ds_write_b128, same XOR involution as conv)
// so the compute phase matches conv's proven inner loop (no cvt on the MFMA dep chain;
// each A elem converted once per block, not twice). A-loads software-pipelined 1-deep
// (T14 issue-early/write-late) via two named reg banks, statically unrolled (rule #20).
// k_group grid reordered (bp,d,g) so d-tile pairs sharing A-rows land on the same XCD.

typedef __bf16  bf16x8 __attribute__((ext_vector_type(8)));
typedef float   f32x4  __attribute__((ext_vector_type(4)));

__device__ __forceinline__ uint16_t f2bf(float f) {
    union { float f; uint32_t u; } x; x.f = f;
    uint32_t r = x.u + 0x7FFFu + ((x.u >> 16) & 1u);   // RTNE
    return (uint16_t)(r >> 16);
}
// async global->LDS, 16B per lane. LDS dest = wave-uniform base + lane*16 (HW rule).
template <typename T>
__device__ __forceinline__ void gl2lds16(const T* g, T* l) {
    __builtin_amdgcn_global_load_lds(
        (const __attribute__((address_space(1))) uint32_t*)g,
        (__attribute__((address_space(3))) uint32_t*)l, 16, 0, 0);
}

// ---------------- fp32 -> bf16 tiled transpose: in (R,C) f32 -> out (C,R) bf16, z = matrix
__global__ void transpose_cvt(const float* __restrict__ in, uint16_t* __restrict__ out,
                              int R, int C) {
    __shared__ float tile[32][33];
    const float* inm = in + (size_t)blockIdx.z * R * C;
    uint16_t* outm = out + (size_t)blockIdx.z * R * C;
    int c0 = blockIdx.x * 32, r0 = blockIdx.y * 32;
    int tx = threadIdx.x, ty = threadIdx.y;            // (32, 8)
    #pragma unroll
    for (int i = 0; i < 32; i += 8)
        tile[ty + i][tx] = inm[(size_t)(r0 + ty + i) * C + (c0 + tx)];
    __syncthreads();
    #pragma unroll
    for (int i = 0; i < 32; i += 8)
        outm[(size_t)(c0 + ty + i) * R + (r0 + tx)] = f2bf(tile[tx][ty + i]);
}

// ---------------- Kernel 1: gathered grouped GEMM -> intermediate (32*1024+64, 256) bf16
// M=128 (2 batches x 64 s), N=128 (d-tile), K=512. 4 waves 2x2, per-wave 64x64.
// A: x f32 rows -> regs -> bf16 -> ds_write (XOR involution), 1-deep pipelined.
// B: Wt bf16 via global_load_lds (unchanged). Compute phase = conv's inner loop.
// grid: (x=16 bp, y=2 d-tiles, z=16 groups) -- d-pairs 16 apart => same XCD, A fetched once.
__global__ __launch_bounds__(256, 2)
void k_group_gemm(const float*    __restrict__ x,    // (32,1024,512) f32
                  const int*      __restrict__ idx,  // (16,64)
                  const uint16_t* __restrict__ Wt,   // (16,256,512) bf16 (W^T per group)
                  const float*    __restrict__ bias, // (16,256) f32
                  uint16_t*       __restrict__ interm) {
    __shared__ uint16_t smemA[8192];                  // 128 x 64 bf16, 16 KB, 8-slot xor
    __shared__ uint16_t smemB[8192];                  // 128 x 64 bf16, 16 KB, 8-slot xor
    __shared__ int sidx[64];
    const int tid  = threadIdx.x;
    const int bp   = blockIdx.x;                      // batches 2bp, 2bp+1
    const int n0   = blockIdx.y * 128;                // d tile base
    const int g    = blockIdx.z;
    const int wave = tid >> 6, lane = tid & 63;
    const int quad = lane >> 4, l15 = lane & 15;
    const int mw = (wave & 1) * 64, nw = (wave >> 1) * 64;

    if (tid < 64) sidx[tid] = idx[g * 64 + tid];
    __syncthreads();

    const int l8r = lane >> 3;
    const int gc8 = ((lane & 7) ^ l8r) * 8;           // xor-swizzled 8-elem chunk

    uint32_t aoffF[4], boff[4];
    #pragma unroll
    for (int is = 0; is < 4; ++is) {
        int r = wave * 32 + is * 8 + l8r;             // tile row 0..127
        int b = bp * 2 + (r >> 6), s = r & 63;
        aoffF[is] = ((uint32_t)b * 1024u + (uint32_t)sidx[s]) * 512u + (uint32_t)gc8;
        boff[is]  = ((uint32_t)(g * 256 + n0 + r)) * 512u + (uint32_t)gc8;
    }

    // A loads: 8 f32 per thread per is (2x f32x4), into a named reg bank.
    auto loadA = [&](int kb, f32x4* dst) {
        #pragma unroll
        for (int is = 0; is < 4; ++is) {
            const float* p = x + aoffF[is] + (uint32_t)kb * 64u;
            dst[2 * is]     = *(const f32x4*)p;
            dst[2 * is + 1] = *(const f32x4*)(p + 4);
        }
    };
    // cvt + ds_write bank into smemA (linear [row][slot*8], source pre-swizzled)
    auto stageA = [&](const f32x4* src) {
        #pragma unroll
        for (int is = 0; is < 4; ++is) {
            bf16x8 o;
            #pragma unroll
            for (int j = 0; j < 4; ++j) {
                o[j]     = (__bf16)src[2 * is][j];
                o[j + 4] = (__bf16)src[2 * is + 1][j];
            }
            *(bf16x8*)&smemA[(wave * 32 + is * 8 + l8r) * 64 + (lane & 7) * 8] = o;
        }
    };
    auto stageB = [&](int kb) {
        #pragma unroll
        for (int is = 0; is < 4; ++is)
            gl2lds16(Wt + boff[is] + (uint32_t)kb * 64u, &smemB[(wave * 32 + is * 8) * 64]);
    };

    f32x4 acc[4][4];
    #pragma unroll
    for (int i = 0; i < 4; ++i)
        #pragma unroll
        for (int j = 0; j < 4; ++j)
            #pragma unroll
            for (int c = 0; c < 4; ++c) acc[i][j][c] = 0.f;

    auto compute = [&]() {
        #pragma unroll
        for (int ks = 0; ks < 2; ++ks) {
            const int kc = ks * 4 + quad;
            bf16x8 af[4], bfr[4];
            #pragma unroll
            for (int i = 0; i < 4; ++i) {
                int m = mw + i * 16 + l15;
                af[i] = *(const bf16x8*)&smemA[(m * 8 + (kc ^ (m & 7))) * 8];
            }
            #pragma unroll
            for (int j = 0; j < 4; ++j) {
                int n = nw + j * 16 + l15;
                bfr[j] = *(const bf16x8*)&smemB[(n * 8 + (kc ^ (n & 7))) * 8];
            }
            #pragma unroll
            for (int i = 0; i < 4; ++i)
                #pragma unroll
                for (int j = 0; j < 4; ++j)
                    acc[i][j] = __builtin_amdgcn_mfma_f32_16x16x32_bf16(af[i], bfr[j], acc[i][j], 0, 0, 0);
        }
    };

    f32x4 a0[8], a1[8];                               // two named banks (static indexing)
    loadA(0, a0);
    #pragma unroll
    for (int kp = 0; kp < 4; ++kp) {
        const int kb = kp * 2;
        // even step: stage from a0, prefetch kb+1 into a1 before the barrier
        stageA(a0); stageB(kb);
        loadA(kb + 1, a1);
        __syncthreads();                              // drains vmem + lds writes
        compute();
        __syncthreads();
        // odd step: stage from a1, prefetch kb+2 into a0
        stageA(a1); stageB(kb + 1);
        if (kb + 2 < 8) loadA(kb + 2, a0);
        __syncthreads();
        compute();
        __syncthreads();
    }

    // epilogue: +bias(f32), store bf16 into interm rows (b*1024 + g*64 + s)
    #pragma unroll
    for (int j = 0; j < 4; ++j) {
        int col = n0 + nw + j * 16 + l15;
        float bv = bias[g * 256 + col];
        #pragma unroll
        for (int i = 0; i < 4; ++i) {
            int mbase = mw + i * 16 + quad * 4;
            #pragma unroll
            for (int r = 0; r < 4; ++r) {
                int m = mbase + r;
                int b = bp * 2 + (m >> 6), s = m & 63;
                interm[((size_t)b * 1024 + g * 64 + s) * 256 + col] = f2bf(acc[i][j][r] + bv);
            }
        }
    }
}

// ---------------- Kernel 2: conv as GEMM (R13 exact copy). Block 128(t) x 256(o),
// per-wave 64x128. grid: (x=32 batches fastest, y=8 t-tiles, z=2 o-tiles).
__global__ __launch_bounds__(256, 2)
void k_conv_gemm(const uint16_t* __restrict__ interm, // (32*1024+64, 256) bf16
                 const uint16_t* __restrict__ cwT,    // (512, 8192) bf16: [o][k*256+c]
                 const float*    __restrict__ cb,     // (512) f32
                 float*          __restrict__ y) {    // (32, 993, 512) f32
    __shared__ uint16_t smem[8192 + 16384];           // A:[0,8192) B:[8192,24576) 48KB
    const int tid  = threadIdx.x;
    const int n0   = blockIdx.z * 256;                // out-channel tile (slowest)
    const int t0   = blockIdx.y * 128;                // time tile
    const int nb   = blockIdx.x;                      // batch (fastest)
    const int wave = tid >> 6, lane = tid & 63;
    const int quad = lane >> 4, l15 = lane & 15;
    const int mw = (wave & 1) * 64;                   // wave row base (2 row-waves)
    const int nw = (wave >> 1) * 128;                 // wave col base (2 col-waves)

    const int l8r = lane >> 3;
    const int gc8 = ((lane & 7) ^ l8r) * 8;           // xor-swizzled 8-elem chunk

    uint32_t aoff[4], boff[8];
    #pragma unroll
    for (int is = 0; is < 4; ++is) {
        int r = wave * 32 + is * 8 + l8r;             // A tile row 0..127
        aoff[is] = ((uint32_t)(nb * 1024 + t0 + r)) * 256u + gc8;
    }
    #pragma unroll
    for (int is = 0; is < 8; ++is) {
        int r = wave * 64 + is * 8 + l8r;             // B tile row 0..255
        boff[is] = ((uint32_t)(n0 + r)) * 8192u + gc8;
    }

    f32x4 acc[4][8];
    #pragma unroll
    for (int i = 0; i < 4; ++i)
        #pragma unroll
        for (int j = 0; j < 8; ++j)
            #pragma unroll
            for (int c = 0; c < 4; ++c) acc[i][j][c] = 0.f;

    for (int kb = 0; kb < 128; ++kb) {                // K = 8192, BK = 64
        const int k  = kb >> 2;                       // conv tap 0..31
        const int c0 = (kb & 3) * 64;                 // channel block
        #pragma unroll
        for (int is = 0; is < 4; ++is)
            gl2lds16(interm + aoff[is] + (uint32_t)k * 256u + c0,
                     &smem[(wave * 32 + is * 8) * 64]);
        #pragma unroll
        for (int is = 0; is < 8; ++is)
            gl2lds16(cwT + boff[is] + (uint32_t)kb * 64u,
                     &smem[8192 + (wave * 64 + is * 8) * 64]);
        __syncthreads();
        #pragma unroll
        for (int ks = 0; ks < 2; ++ks) {
            const int kc = ks * 4 + quad;
            bf16x8 af[4], bfr[8];
            #pragma unroll
            for (int i = 0; i < 4; ++i) {
                int m = mw + i * 16 + l15;
                af[i] = *(const bf16x8*)&smem[(m * 8 + (kc ^ (m & 7))) * 8];
            }
            #pragma unroll
            for (int j = 0; j < 8; ++j) {
                int n = nw + j * 16 + l15;
                bfr[j] = *(const bf16x8*)&smem[8192 + (n * 8 + (kc ^ (n & 7))) * 8];
            }
            #pragma unroll
            for (int i = 0; i < 4; ++i)
                #pragma unroll
                for (int j = 0; j < 8; ++j)
                    acc[i][j] = __builtin_amdgcn_mfma_f32_16x16x32_bf16(af[i], bfr[j], acc[i][j], 0, 0, 0);
        }
        __syncthreads();
    }

    // epilogue: +conv_b(f32), leaky relu, store f32, valid t < 993
    #pragma unroll
    for (int j = 0; j < 8; ++j) {
        int col = n0 + nw + j * 16 + l15;
        float bv = cb[col];
        #pragma unroll
        for (int i = 0; i < 4; ++i) {
            int tb = t0 + mw + i * 16 + quad * 4;
            #pragma unroll
            for (int r = 0; r < 4; ++r) {
                int t = tb + r;
                if (t < 993) {
                    float v = acc[i][j][r] + bv;
                    v = (v >= 0.f) ? v : 0.2f * v;
                    y[((size_t)nb * 993 + t) * 512 + col] = v;
                }
            }
        }
    }
}

extern "C" void kernel_launch(void* const* d_in, const int* in_sizes, int n_in,
                              void* d_out, int out_size, void* d_ws, size_t ws_size,
                              hipStream_t stream) {
    const float* x   = (const float*)d_in[0];   // (32,1024,512) f32
    const int*   idx = (const int*)  d_in[1];   // (16,64) i32
    const float* W   = (const float*)d_in[2];   // (16,512,256) f32
    const float* b   = (const float*)d_in[3];   // (16,256) f32
    const float* cw  = (const float*)d_in[4];   // (32,256,512) f32
    const float* cb  = (const float*)d_in[5];   // (512) f32
    float* out = (float*)d_out;                 // (32,993,512) f32

    // workspace (bf16 elems): interm (32832,256) | Wt (16,256,512) | cwT (512,8192)  ~29.4 MB
    uint16_t* interm = (uint16_t*)d_ws;
    uint16_t* Wt  = interm + (size_t)32832 * 256;
    uint16_t* cwT = Wt + (size_t)16 * 256 * 512;

    // W (g,512,256) f32 -> Wt (g,256,512) bf16
    transpose_cvt<<<dim3(256 / 32, 512 / 32, 16), dim3(32, 8), 0, stream>>>(W, Wt, 512, 256);
    // conv_w (8192,512) f32 -> cwT (512,8192) bf16
    transpose_cvt<<<dim3(512 / 32, 8192 / 32, 1), dim3(32, 8), 0, stream>>>(cw, cwT, 8192, 512);

    k_group_gemm<<<dim3(16, 2, 16), 256, 0, stream>>>(x, idx, Wt, b, interm);
    k_conv_gemm <<<dim3(32, 8, 2),  256, 0, stream>>>(interm, cwT, cb, out);
}